// Round 12
// baseline (259.087 us; speedup 1.0000x reference)
//
#include <hip/hip_runtime.h>
#include <hip/hip_bf16.h>

// Problem constants
#define BB 2
#define SS 1024
#define DD 1024
#define NH 16
#define DH 64
#define MM 8
#define RR 128
#define NN 256
#define NT (BB*SS)          // 2048 tokens

using bf16 = __hip_bfloat16;

typedef __attribute__((ext_vector_type(8))) short short8;   // 8 bf16 (4 VGPRs) MFMA A/B frag
typedef __attribute__((ext_vector_type(4))) short short4v;  // 8-byte unit
typedef __attribute__((ext_vector_type(4))) float f32x4;    // MFMA C/D frag

// raw v_exp_f32 (2^x)
#define EXP2F(x) __builtin_amdgcn_exp2f(x)

// async 16B global->LDS (lane i lands at ldsbase + i*16; ldsbase wave-uniform)
#define GLD16(g, l) __builtin_amdgcn_global_load_lds( \
    (const __attribute__((address_space(1))) void*)(g), \
    (__attribute__((address_space(3))) void*)(l), 16, 0, 0)

// Load 8 bf16 (as shorts) from LDS via two 8B reads (base only 8B-aligned).
__device__ __forceinline__ short8 lds_load8(const short* p) {
    short4v a = *(const short4v*)p;
    short4v b = *(const short4v*)(p + 4);
    short8 r;
    r[0] = a[0]; r[1] = a[1]; r[2] = a[2]; r[3] = a[3];
    r[4] = b[0]; r[5] = b[1]; r[6] = b[2]; r[7] = b[3];
    return r;
}

// ---- staging helper: NR rows x 64 cols bf16, GLD16 + XOR chunk swizzle ----
template <int NR>
__device__ __forceinline__ void stage_tile(const bf16* __restrict__ src, int k0,
                                           bf16* lds, int wave, int lane) {
#pragma unroll
    for (int i = 0; i < NR / 32; ++i) {
        const int L = i * 256 + wave * 64 + lane;
        const int row = L >> 3;
        const int gch = (L & 7) ^ ((row >> 1) & 7);
        GLD16(src + (size_t)row * DD + k0 + gch * 8, &lds[(i * 256 + wave * 64) * 8]);
    }
}

// MFMA fragment from swizzled LDS tile: row rc, k-slot (kk*4+quad)
__device__ __forceinline__ short8 fragld(const bf16* lds, int rc, int kk, int quad) {
    int slot = (kk * 4 + quad) ^ ((rc >> 1) & 7);
    return *(const short8*)&((const short*)lds)[(rc * 8 + slot) * 8];
}

// -------- 128x128 GEMM body, BK=64, 2-buffer 1-deep prefetch (R8) ---------
// 4 waves (2x2), each 64x64 (4x4 frags). LDS 64 KB -> 2 blocks/CU.
// Prefetch k+1 BEFORE compute k; single __syncthreads per step.
__device__ __forceinline__ void gemm128_pipe1(
    const bf16* __restrict__ A, const bf16* __restrict__ Bt, bf16* __restrict__ C,
    int Nz, int m0, int n0, bf16* As, bf16* Bs,
    int wave, int lane, int quad, int l15) {
    const int wr = wave >> 1, wc = wave & 1;
    f32x4 acc[4][4];
#pragma unroll
    for (int i = 0; i < 4; ++i)
#pragma unroll
        for (int j = 0; j < 4; ++j) acc[i][j] = (f32x4)0.f;

    const bf16* Ab = A + (size_t)m0 * DD;
    const bf16* Bb = Bt + (size_t)n0 * DD;

    stage_tile<128>(Ab, 0, As, wave, lane);
    stage_tile<128>(Bb, 0, Bs, wave, lane);
    __syncthreads();

    for (int it = 0; it < 16; ++it) {
        const int buf = it & 1;
        const bf16* Asc = As + buf * 8192;
        const bf16* Bsc = Bs + buf * 8192;
        if (it < 15) {   // issue next step's loads first (latency hiding)
            stage_tile<128>(Ab, (it + 1) * 64, As + (buf ^ 1) * 8192, wave, lane);
            stage_tile<128>(Bb, (it + 1) * 64, Bs + (buf ^ 1) * 8192, wave, lane);
        }
#pragma unroll
        for (int kk = 0; kk < 2; ++kk) {
            short8 aF[4], bF[4];
#pragma unroll
            for (int bi = 0; bi < 4; ++bi) aF[bi] = fragld(Asc, wr * 64 + bi * 16 + l15, kk, quad);
#pragma unroll
            for (int bj = 0; bj < 4; ++bj) bF[bj] = fragld(Bsc, wc * 64 + bj * 16 + l15, kk, quad);
#pragma unroll
            for (int bi = 0; bi < 4; ++bi)
#pragma unroll
                for (int bj = 0; bj < 4; ++bj)
                    acc[bi][bj] = __builtin_amdgcn_mfma_f32_16x16x32_bf16(aF[bi], bF[bj], acc[bi][bj], 0, 0, 0);
        }
        __syncthreads();   // drains prefetch (overlapped with compute) + reads
    }

#pragma unroll
    for (int bi = 0; bi < 4; ++bi)
#pragma unroll
        for (int bj = 0; bj < 4; ++bj)
#pragma unroll
            for (int r = 0; r < 4; ++r) {
                int row = m0 + wr * 64 + bi * 16 + quad * 4 + r;
                int col = n0 + wc * 64 + bj * 16 + l15;
                C[(size_t)row * Nz + col] = __float2bfloat16(acc[bi][bj][r]);
            }
}

// ---------------- proj launch: 352 GEMM blocks + conv2 backfill ------------
// GEMM works (XCD-swizzled over 352 = 8x44), 128x128 tiles:
//   wk 0..255:  z = wk>>7 -> allh_qk / allh_v (xb @ f[z]), 16x8 tiles
//   wk 256..351: wg GEMM [2048x768] (16x6 tiles)
// blocks 352..3423: conv2 transpose tiles (qk_r, v_r, W_O), pure-BW backfill.
struct ProjArgs {
    const bf16 *xb, *f0, *f1, *wg;
    bf16 *allh0, *allh1, *lg;
    const float* csrc[3];
    bf16* cdst[3];
};

__global__ __launch_bounds__(256, 2) void mfma_proj(ProjArgs P) {
    __shared__ __align__(16) char smem[65536];   // 2x(128x64) x 2 (A,B) bf16
    const int bidx = blockIdx.x;
    const int tid = threadIdx.x;

    if (bidx >= 352) {   // ---- conv2 transpose path (K=R=1024, G=1) ----
        float (*tile)[33] = (float(*)[33])smem;
        const int cb = bidx - 352;
        const int j = cb >> 10;
        const int t = cb & 1023;
        const int kb = t >> 5, rb = t & 31;
        const int tx = tid & 31, ty0 = tid >> 5;
        const float* s = P.csrc[j] + ((size_t)(kb * 32) * 1024) + rb * 32 + tx;
#pragma unroll
        for (int p = 0; p < 4; ++p)
            tile[ty0 + p * 8][tx] = s[(size_t)(ty0 + p * 8) * 1024];
        __syncthreads();
        bf16* dd = P.cdst[j] + ((size_t)(rb * 32) * 1024) + kb * 32 + tx;
#pragma unroll
        for (int p = 0; p < 4; ++p)
            dd[(size_t)(ty0 + p * 8) * 1024] = __float2bfloat16(tile[tx][ty0 + p * 8]);
        return;
    }

    bf16* As = (bf16*)smem;          // 2 x 128*64
    bf16* Bs = As + 2 * 128 * 64;    // 2 x 128*64
    const int wave = tid >> 6, lane = tid & 63;
    const int quad = lane >> 4, l15 = lane & 15;
    const int wk = (bidx & 7) * 44 + (bidx >> 3);   // XCD swizzle (352 = 8x44)
    if (wk < 256) {
        const int z = wk >> 7;
        const int r = wk & 127;
        gemm128_pipe1(P.xb, z ? P.f1 : P.f0, z ? P.allh1 : P.allh0, 1024,
                      (r >> 3) * 128, (r & 7) * 128, As, Bs, wave, lane, quad, l15);
    } else {
        const int r = wk - 256;
        gemm128_pipe1(P.xb, P.wg, P.lg, 768, (r / 6) * 128, (r % 6) * 128,
                      As, Bs, wave, lane, quad, l15);
    }
}

// ---------------- restore launch: 384 blocks, 3 jobs, 128x128 --------------
// Block 0 additionally zeros the flash pair-counters (restore fully precedes
// flash in stream order, so this handles workspace re-poison every launch).
struct RestZ {
    const bf16* A[3];
    const bf16* Bt[3];
    bf16* C[3];
};

__global__ __launch_bounds__(256, 2) void mfma_restore(RestZ R, int* cnt) {
    __shared__ __align__(16) char smem[65536];
    bf16* As = (bf16*)smem;
    bf16* Bs = As + 2 * 128 * 64;
    const int tid = threadIdx.x;
    if (blockIdx.x == 0) cnt[tid] = 0;   // 256 pair counters
    const int wave = tid >> 6, lane = tid & 63;
    const int quad = lane >> 4, l15 = lane & 15;
    const int wk = (blockIdx.x & 7) * 48 + (blockIdx.x >> 3);   // 384 = 8x48
    const int z = wk >> 7;
    const int r = wk & 127;
    gemm128_pipe1(R.A[z], R.Bt[z], R.C[z], DD, (r >> 3) * 128, (r & 7) * 128,
                  As, Bs, wave, lane, quad, l15);
}

// ---------- W_O: 2-deep pipelined 64x64 tiles, 512 blocks, f32 out ---------
// (R11: reverted to unfused R8 version -- fused split path regressed +2.7us.)
__global__ __launch_bounds__(256, 3) void mfma_wo(
    const bf16* __restrict__ A, const bf16* __restrict__ Bt, float* __restrict__ C) {
    __shared__ __align__(16) bf16 As[3 * 64 * 64];
    __shared__ __align__(16) bf16 Bs[3 * 64 * 64];
    const int tid = threadIdx.x;
    const int wave = tid >> 6, lane = tid & 63;
    const int quad = lane >> 4, l15 = lane & 15;
    const int wr = wave >> 1, wc = wave & 1;
    const int wk = (blockIdx.x & 7) * 64 + (blockIdx.x >> 3);   // 512 = 8x64
    const int m0 = (wk >> 4) * 64, n0 = (wk & 15) * 64;

    f32x4 acc[2][2];
#pragma unroll
    for (int i = 0; i < 2; ++i)
#pragma unroll
        for (int j = 0; j < 2; ++j) acc[i][j] = (f32x4)0.f;

    const bf16* Ab = A + (size_t)m0 * DD;
    const bf16* Bb = Bt + (size_t)n0 * DD;

    stage_tile<64>(Ab, 0, As, wave, lane);
    stage_tile<64>(Bb, 0, Bs, wave, lane);
    stage_tile<64>(Ab, 64, As + 4096, wave, lane);
    stage_tile<64>(Bb, 64, Bs + 4096, wave, lane);

    int cur = 0;
    for (int it = 0; it < 16; ++it) {
        const int k0 = it * 64;
        int nxt = cur + 2; if (nxt >= 3) nxt -= 3;
        if (it < 14) {
            stage_tile<64>(Ab, k0 + 128, As + nxt * 4096, wave, lane);
            stage_tile<64>(Bb, k0 + 128, Bs + nxt * 4096, wave, lane);
            asm volatile("s_waitcnt vmcnt(8)" ::: "memory");
        } else if (it == 14) {
            asm volatile("s_waitcnt vmcnt(4)" ::: "memory");
        } else {
            asm volatile("s_waitcnt vmcnt(0)" ::: "memory");
        }
        __builtin_amdgcn_s_barrier();

        const bf16* Asc = As + cur * 4096;
        const bf16* Bsc = Bs + cur * 4096;
#pragma unroll
        for (int kk = 0; kk < 2; ++kk) {
            short8 aF[2], bF[2];
#pragma unroll
            for (int bi = 0; bi < 2; ++bi) aF[bi] = fragld(Asc, wr * 32 + bi * 16 + l15, kk, quad);
#pragma unroll
            for (int bj = 0; bj < 2; ++bj) bF[bj] = fragld(Bsc, wc * 32 + bj * 16 + l15, kk, quad);
#pragma unroll
            for (int bi = 0; bi < 2; ++bi)
#pragma unroll
                for (int bj = 0; bj < 2; ++bj)
                    acc[bi][bj] = __builtin_amdgcn_mfma_f32_16x16x32_bf16(aF[bi], bF[bj], acc[bi][bj], 0, 0, 0);
        }
        __builtin_amdgcn_s_barrier();
        cur = cur + 1; if (cur == 3) cur = 0;
    }
#pragma unroll
    for (int bi = 0; bi < 2; ++bi)
#pragma unroll
        for (int bj = 0; bj < 2; ++bj)
#pragma unroll
            for (int r = 0; r < 4; ++r) {
                int row = m0 + wr * 32 + bi * 16 + quad * 4 + r;
                int col = n0 + wc * 32 + bj * 16 + l15;
                C[(size_t)row * DD + col] = acc[bi][bj][r];
            }
}

// ---------------- convert1: inputs proj needs (x, qk_f, v_f, Wg) -----------
struct ConvJobs {
    const float* src[9];
    bf16* dst[9];
    int K[9], R[9], G[9];
    int tEnd[9];
};

__global__ void convert_kernel(ConvJobs J) {
    __shared__ float tile[32][33];
    const int b = blockIdx.x;
    int j = 0;
    while (j < 8 && b >= J.tEnd[j]) ++j;
    const int local = b - (j > 0 ? J.tEnd[j - 1] : 0);
    const float* src = J.src[j];
    bf16* dst = J.dst[j];
    const int tid = threadIdx.x;

    if (J.G[j] == 0) {
        size_t base = (size_t)local * 4096 + (size_t)tid * 16;
        const float4* s4 = (const float4*)(src + base);
        short* d = (short*)(dst + base);
#pragma unroll
        for (int c = 0; c < 4; ++c) {
            float4 v = s4[c];
            short4v o;
            bf16 t0 = __float2bfloat16(v.x); o[0] = *(short*)&t0;
            bf16 t1 = __float2bfloat16(v.y); o[1] = *(short*)&t1;
            bf16 t2 = __float2bfloat16(v.z); o[2] = *(short*)&t2;
            bf16 t3 = __float2bfloat16(v.w); o[3] = *(short*)&t3;
            *(short4v*)(d + c * 4) = o;
        }
    } else {
        const int Kj = J.K[j], Rj = J.R[j];
        const int Rb = Rj >> 5, Kb = Kj >> 5;
        const int perG = Kb * Rb;
        const int g = local / perG;
        const int rem = local - g * perG;
        const int kb = rem / Rb, rb = rem - kb * Rb;
        const int tx = tid & 31, ty0 = tid >> 5;
        const float* s = src + ((size_t)(g * Kj + kb * 32) * Rj) + rb * 32 + tx;
#pragma unroll
        for (int p = 0; p < 4; ++p)
            tile[ty0 + p * 8][tx] = s[(size_t)(ty0 + p * 8) * Rj];
        __syncthreads();
        bf16* dd = dst + ((size_t)(g * Rj + rb * 32) * Kj) + kb * 32 + tx;
#pragma unroll
        for (int p = 0; p < 4; ++p)
            dd[(size_t)(ty0 + p * 8) * Kj] = __float2bfloat16(tile[tx][ty0 + p * 8]);
    }
}

// ---------------- fused gates + combine + make_pre (shuffle softmax) -------
__global__ void gate_combine(const bf16* __restrict__ logitsAll,
                             const bf16* __restrict__ allh,
                             bf16* __restrict__ preQ, bf16* __restrict__ preK,
                             bf16* __restrict__ preV) {
    const int t = blockIdx.x;
    const int n = threadIdx.x;   // 256
    const int wave = n >> 6, lane = n & 63;
    __shared__ float wred[3][4];
    __shared__ float sred[3][4];
    __shared__ float gred[3][8];

    float v[3], e[3];
#pragma unroll
    for (int z = 0; z < 3; ++z)
        v[z] = __bfloat162float(logitsAll[(size_t)t * 768 + z * 256 + n]);

    float mz[3];
#pragma unroll
    for (int z = 0; z < 3; ++z) {
        mz[z] = v[z];
#pragma unroll
        for (int off = 1; off <= 32; off <<= 1)
            mz[z] = fmaxf(mz[z], __shfl_xor(mz[z], off));
    }
    if (lane == 0) {
#pragma unroll
        for (int z = 0; z < 3; ++z) wred[z][wave] = mz[z];
    }
    __syncthreads();
    float gmax[3];
#pragma unroll
    for (int z = 0; z < 3; ++z)
        gmax[z] = fmaxf(fmaxf(wred[z][0], wred[z][1]), fmaxf(wred[z][2], wred[z][3]));

    float ws[3];
#pragma unroll
    for (int z = 0; z < 3; ++z) {
        e[z] = __expf(v[z] - gmax[z]);
        ws[z] = e[z];
#pragma unroll
        for (int off = 1; off <= 32; off <<= 1)
            ws[z] += __shfl_xor(ws[z], off);
    }
    if (lane == 0) {
#pragma unroll
        for (int z = 0; z < 3; ++z) sred[z][wave] = ws[z];
    }
    float gs[3];
#pragma unroll
    for (int z = 0; z < 3; ++z) {
        gs[z] = e[z];
#pragma unroll
        for (int off = 1; off <= 16; off <<= 1)
            gs[z] += __shfl_xor(gs[z], off);
    }
    __syncthreads();
    float total[3];
#pragma unroll
    for (int z = 0; z < 3; ++z)
        total[z] = sred[z][0] + sred[z][1] + sred[z][2] + sred[z][3];
    if ((n & 31) == 0) {
#pragma unroll
        for (int z = 0; z < 3; ++z) gred[z][n >> 5] = gs[z] / total[z];
    }
    __syncthreads();

    float gv[3][8];
#pragma unroll
    for (int z = 0; z < 3; ++z) {
        float tot = 0.f;
#pragma unroll
        for (int m = 0; m < 8; ++m) tot += gred[z][m];
        float inv = 1.0f / (tot + 1e-8f);
#pragma unroll
        for (int m = 0; m < 8; ++m) gv[z][m] = gred[z][m] * inv;
    }

    const int r0 = n & 127;
    const int half = n >> 7;
    const bf16* src_qk = allh + (size_t)t * 1024;
    const bf16* src_v  = allh + (size_t)NT * DD + (size_t)t * 1024;
    float hq = 0.f, hk = 0.f, hv = 0.f;
#pragma unroll
    for (int m = 0; m < 8; ++m) {
        float aqk = __bfloat162float(src_qk[m * 128 + r0]);
        float av  = __bfloat162float(src_v[m * 128 + r0]);
        hq += aqk * gv[0][m];
        hk += aqk * gv[1][m];
        hv += av  * gv[2][m];
    }
    __syncthreads();   // all allh_v reads complete before in-place preV writes
#pragma unroll
    for (int mm = 0; mm < 4; ++mm) {
        int m = half * 4 + mm;
        size_t o = (size_t)t * 1024 + m * 128 + r0;
        preQ[o] = __float2bfloat16(hq * gv[0][m]);
        preK[o] = __float2bfloat16(hk * gv[1][m]);
        preV[o] = __float2bfloat16(hv * gv[2][m]);
    }
}

// -------------- Flash attention, hybrid split-kt + in-kernel combine -------
// qt>=8 split into two <=8-iter halves; qt<8 unsplit (direct bf16 out).
// R11: the split-half merge happens IN this kernel via a last-block-wins
// device-scope atomic ticket (G16 pattern): each half writes its partials,
// threadfence + barrier, lane0 atomicAdd on cnt[pair]; the SECOND finisher
// acquires, reads only the OTHER half's partial/ml, merges against its own
// registers, and writes final bf16 rows. Kills the combine kernel + launch.
#define LDK 68

// rank -> work: (split<<5) | (qt<<1) | half, ordered by descending kt-iters
__device__ const int FW24[24] = {
    62, 63, 60, 61, 14,    // len 8: S15h0 S15h1 S14h0 S14h1 U7
    58, 59, 56, 12,        // len 7: S13h0 S13h1 S12h0 U6
    57, 54, 55, 52, 10,    // len 6: S12h1 S11h0 S11h1 S10h0 U5
    53, 50, 51, 48, 8,     // len 5: S10h1 S9h0 S9h1 S8h0 U4
    49, 6,                 // len 4: S8h1 U3
    4, 2, 0                // U2 U1 U0
};

__global__ __launch_bounds__(256) void flash_attn_hybrid(
    const bf16* __restrict__ Q, const bf16* __restrict__ K,
    const bf16* __restrict__ V, bf16* __restrict__ out,
    float* __restrict__ Opart, float* __restrict__ ml, int* __restrict__ cnt) {
    const int bx = blockIdx.x;
    const int e = FW24[bx >> 5];
    const int bh = bx & 31;
    const int split = e >> 5;
    const int qt = (e >> 1) & 15;
    const int half = e & 1;
    const int h0 = (qt + 2) >> 1;
    const int kt_lo = (split && half) ? h0 : 0;
    const int kt_hi = (split && !half) ? h0 : (qt + 1);
    const int b = bh >> 4;
    const int h = bh & 15;

    const int tid = threadIdx.x;
    const int wave = tid >> 6;
    const int lane = tid & 63;
    const int quad = lane >> 4;
    const int l15 = lane & 15;

    __shared__ short Ks[2][64 * 64];      // 16 KB, GLD16 + XOR swizzle
    __shared__ short Vt[2][64 * LDK];     // 17 KB, transposed
    __shared__ short Ps[4 * 16 * LDK];    // per-wave P[m][kr]
    __shared__ int tick;

    const int q_row = qt * 64 + wave * 16 + l15;
    const bf16* qptr = Q + (size_t)(b * SS + q_row) * DD + h * DH + quad * 8;
    short8 aq0 = *(const short8*)qptr;
    short8 aq1 = *(const short8*)(qptr + 32);

    // V staging geometry (per thread)
    const int krp = tid & 31;
    const int dhb = (tid >> 5) * 8;

    float m_r[4], l_r[4];
    f32x4 o[4];
#pragma unroll
    for (int r = 0; r < 4; ++r) { m_r[r] = -3.0e38f; l_r[r] = 0.f; }
#pragma unroll
    for (int cc = 0; cc < 4; ++cc) o[cc] = (f32x4)0.f;

    const float SCL2 = 0.18033688f;   // 0.125 * log2(e)

    // ---- prologue: stage tile kt_lo into buf 0 ----
    {
#pragma unroll
        for (int i = 0; i < 2; ++i) {
            const int L = i * 256 + wave * 64 + lane;
            const int row = L >> 3;
            const int gch = (L & 7) ^ ((row >> 1) & 7);
            GLD16(K + (size_t)(b * SS + kt_lo * 64 + row) * DD + h * DH + gch * 8,
                  &Ks[0][(i * 256 + wave * 64) * 8]);
        }
        const bf16* s0 = V + (size_t)(b * SS + kt_lo * 64 + 2 * krp) * DD + h * DH + dhb;
        short8 r0 = *(const short8*)s0;
        short8 r1 = *(const short8*)(s0 + DD);
#pragma unroll
        for (int i = 0; i < 8; ++i) {
            unsigned int pk = (unsigned short)r0[i] | ((unsigned int)(unsigned short)r1[i] << 16);
            *(unsigned int*)&Vt[0][(dhb + i) * LDK + 2 * krp] = pk;
        }
        __syncthreads();
    }

    for (int kt = kt_lo; kt < kt_hi; ++kt) {
        const int buf = (kt - kt_lo) & 1;
        const bool pf = (kt + 1 < kt_hi);
        short8 pr0, pr1;
        if (pf) {
            // issue next K tile (async direct-to-LDS) and next V loads (VGPR)
#pragma unroll
            for (int i = 0; i < 2; ++i) {
                const int L = i * 256 + wave * 64 + lane;
                const int row = L >> 3;
                const int gch = (L & 7) ^ ((row >> 1) & 7);
                GLD16(K + (size_t)(b * SS + (kt + 1) * 64 + row) * DD + h * DH + gch * 8,
                      &Ks[buf ^ 1][(i * 256 + wave * 64) * 8]);
            }
            const bf16* s0 = V + (size_t)(b * SS + (kt + 1) * 64 + 2 * krp) * DD + h * DH + dhb;
            pr0 = *(const short8*)s0;
            pr1 = *(const short8*)(s0 + DD);
        }

        // ---- compute current tile ----
        const short* KsB = Ks[buf];
        f32x4 s[4];
#pragma unroll
        for (int cc = 0; cc < 4; ++cc) {
            int n = cc * 16 + l15;
            int sl0 = quad ^ ((n >> 1) & 7);
            int sl1 = (quad + 4) ^ ((n >> 1) & 7);
            short8 bk0 = *(const short8*)&KsB[(n * 8 + sl0) * 8];
            short8 bk1 = *(const short8*)&KsB[(n * 8 + sl1) * 8];
            f32x4 acc = (f32x4)0.f;
            acc = __builtin_amdgcn_mfma_f32_16x16x32_bf16(aq0, bk0, acc, 0, 0, 0);
            acc = __builtin_amdgcn_mfma_f32_16x16x32_bf16(aq1, bk1, acc, 0, 0, 0);
            s[cc] = acc;
        }

        const bool diag = (kt == qt);
#pragma unroll
        for (int cc = 0; cc < 4; ++cc) {
#pragma unroll
            for (int r = 0; r < 4; ++r) {
                float v = s[cc][r] * SCL2;
                if (diag) {
                    int row_rel = wave * 16 + quad * 4 + r;
                    int col_rel = cc * 16 + l15;
                    if (col_rel > row_rel) v = -3.0e38f;
                }
                s[cc][r] = v;
            }
        }

        // tile row-max
        float mx[4];
#pragma unroll
        for (int r = 0; r < 4; ++r) {
            float m2 = fmaxf(fmaxf(s[0][r], s[1][r]), fmaxf(s[2][r], s[3][r]));
            m2 = fmaxf(m2, __shfl_xor(m2, 1));
            m2 = fmaxf(m2, __shfl_xor(m2, 2));
            m2 = fmaxf(m2, __shfl_xor(m2, 4));
            m2 = fmaxf(m2, __shfl_xor(m2, 8));
            mx[r] = m2;
        }
        // defer-max: only pay alpha-exp + o/l rescale when max grew by >8
        bool grew = false;
#pragma unroll
        for (int r = 0; r < 4; ++r) grew = grew || (mx[r] > m_r[r] + 8.f);
        float alpha[4];
        const bool need = __any(grew);
        if (need) {
#pragma unroll
            for (int r = 0; r < 4; ++r) {
                float nm = fmaxf(m_r[r], mx[r]);
                alpha[r] = EXP2F(m_r[r] - nm);
                m_r[r] = nm;
            }
        }

        float p[4][4];
#pragma unroll
        for (int r = 0; r < 4; ++r) {
            float rs = 0.f;
#pragma unroll
            for (int cc = 0; cc < 4; ++cc) {
                float e2 = EXP2F(s[cc][r] - m_r[r]);
                p[cc][r] = e2;
                rs += e2;
            }
            rs += __shfl_xor(rs, 1);
            rs += __shfl_xor(rs, 2);
            rs += __shfl_xor(rs, 4);
            rs += __shfl_xor(rs, 8);
            if (need) l_r[r] = l_r[r] * alpha[r] + rs;
            else      l_r[r] += rs;
        }
        if (need) {
#pragma unroll
            for (int cc = 0; cc < 4; ++cc)
#pragma unroll
                for (int r = 0; r < 4; ++r) o[cc][r] *= alpha[r];
        }

        // P: C-layout -> wave-private LDS slab -> A-layout (no barrier needed)
        short* pw = &Ps[wave * 16 * LDK];
#pragma unroll
        for (int cc = 0; cc < 4; ++cc)
#pragma unroll
            for (int r = 0; r < 4; ++r) {
                bf16 hb = __float2bfloat16(p[cc][r]);
                pw[(quad * 4 + r) * LDK + cc * 16 + l15] = *(short*)&hb;
            }

        short8 ap0 = lds_load8(&pw[l15 * LDK + quad * 8]);
        short8 ap1 = lds_load8(&pw[l15 * LDK + 32 + quad * 8]);

        const short* VtB = Vt[buf];
#pragma unroll
        for (int cc = 0; cc < 4; ++cc) {
            short8 bv0 = lds_load8(&VtB[(cc * 16 + l15) * LDK + quad * 8]);
            short8 bv1 = lds_load8(&VtB[(cc * 16 + l15) * LDK + 32 + quad * 8]);
            o[cc] = __builtin_amdgcn_mfma_f32_16x16x32_bf16(ap0, bv0, o[cc], 0, 0, 0);
            o[cc] = __builtin_amdgcn_mfma_f32_16x16x32_bf16(ap1, bv1, o[cc], 0, 0, 0);
        }

        // ---- write V prefetch into the other buffer, then the ONE barrier ----
        if (pf) {
#pragma unroll
            for (int i = 0; i < 8; ++i) {
                unsigned int pk = (unsigned short)pr0[i] | ((unsigned int)(unsigned short)pr1[i] << 16);
                *(unsigned int*)&Vt[buf ^ 1][(dhb + i) * LDK + 2 * krp] = pk;
            }
        }
        __syncthreads();
    }

    if (!split) {
        // ---- normalize in-register and write bf16 directly ----
        float inv[4];
#pragma unroll
        for (int r = 0; r < 4; ++r) inv[r] = 1.0f / l_r[r];
#pragma unroll
        for (int cc = 0; cc < 4; ++cc)
#pragma unroll
            for (int r = 0; r < 4; ++r) {
                int row = qt * 64 + wave * 16 + quad * 4 + r;
                out[(size_t)(b * SS + row) * DD + h * DH + cc * 16 + l15] =
                    __float2bfloat16(o[cc][r] * inv[r]);
            }
    } else {
        // ---- write own partials (unnormalized O, m, l in log2 domain) ----
        const int pairIdx = bh * 8 + (qt - 8);
        const int idx = pairIdx * 2 + half;
        float* ob = Opart + (size_t)idx * 4096;
#pragma unroll
        for (int cc = 0; cc < 4; ++cc)
#pragma unroll
            for (int r = 0; r < 4; ++r) {
                int row = wave * 16 + quad * 4 + r;
                ob[row * 64 + cc * 16 + l15] = o[cc][r];
            }
        if (l15 == 0) {
#pragma unroll
            for (int r = 0; r < 4; ++r) {
                int row = wave * 16 + quad * 4 + r;
                ml[(size_t)idx * 128 + row] = m_r[r];
                ml[(size_t)idx * 128 + 64 + row] = l_r[r];
            }
        }

        // ---- last-block-wins merge (device-scope ticket) ----
        __threadfence();          // make my partial writes visible device-wide
        __syncthreads();          // all threads' stores issued before ticket
        if (tid == 0) tick = atomicAdd(&cnt[pairIdx], 1);
        __syncthreads();
        if (tick == 1) {          // I'm the second finisher: merge
            __threadfence();      // acquire the other half's writes
            const int other = pairIdx * 2 + (half ^ 1);
            const float* o1b = Opart + (size_t)other * 4096;
            float w0[4], w1[4], inv[4];
#pragma unroll
            for (int r = 0; r < 4; ++r) {
                int row = wave * 16 + quad * 4 + r;
                float m1 = ml[(size_t)other * 128 + row];
                float l1 = ml[(size_t)other * 128 + 64 + row];
                float ms = fmaxf(m_r[r], m1);
                w0[r] = EXP2F(m_r[r] - ms);
                w1[r] = EXP2F(m1 - ms);
                inv[r] = 1.0f / (l_r[r] * w0[r] + l1 * w1[r]);
            }
#pragma unroll
            for (int cc = 0; cc < 4; ++cc)
#pragma unroll
                for (int r = 0; r < 4; ++r) {
                    int row = wave * 16 + quad * 4 + r;
                    float ov = o1b[row * 64 + cc * 16 + l15];
                    float v = (o[cc][r] * w0[r] + ov * w1[r]) * inv[r];
                    int grow = qt * 64 + row;
                    out[(size_t)(b * SS + grow) * DD + h * DH + cc * 16 + l15] =
                        __float2bfloat16(v);
                }
        }
    }
}

extern "C" void kernel_launch(void* const* d_in, const int* in_sizes, int n_in,
                              void* d_out, int out_size, void* d_ws, size_t ws_size,
                              hipStream_t stream) {
    const float* x    = (const float*)d_in[0];
    const float* qk_f = (const float*)d_in[1];
    const float* qk_r = (const float*)d_in[2];
    const float* v_f  = (const float*)d_in[3];
    const float* v_r  = (const float*)d_in[4];
    const float* Wg_q = (const float*)d_in[5];
    const float* Wg_k = (const float*)d_in[6];
    const float* Wg_v = (const float*)d_in[7];
    const float* W_O  = (const float*)d_in[8];

    // Workspace (256 MiB). Layout:
    //  0..4    xb      -> preQ      -> attnb
    //  4..8    wg_bt(4..5.5)+pad    -> preK
    //  5.5..9.5 fbt    (dead after proj)
    //  8..12           -> Kb
    //  9.5..12.5 logits (dead after gate_combine)
    //  12..16          -> Vb
    //  16..18 qkr_bt | 18..20 vr_bt | 20..22 wo_bt (stable)
    //  32..40 Opart (512 x 16KB f32) | 48..48.25 ml | 49 cnt (1KB, zeroed
    //  by restore block 0 each launch -- handles workspace re-poison)
    // d_out: allh [0..8 MiB] -> preV in-place over allh_v -> Qb [0..4] -> f32 out
    char* w = (char*)d_ws;
    const size_t MB = 1 << 20;
    bf16* xb     = (bf16*)(w + 0);
    bf16* wg_bt  = (bf16*)(w + 4 * MB);
    bf16* fbt    = (bf16*)(w + (size_t)(5.5 * MB));
    bf16* logits = (bf16*)(w + (size_t)(9.5 * MB));   // [2048][768] = 3 MiB
    bf16* qkr_bt = (bf16*)(w + 16 * MB);
    bf16* vr_bt  = (bf16*)(w + 18 * MB);
    bf16* wo_bt  = (bf16*)(w + 20 * MB);
    bf16* preQ   = (bf16*)(w + 0);
    bf16* preK   = (bf16*)(w + 4 * MB);
    bf16* Kb     = (bf16*)(w + 8 * MB);
    bf16* Vb     = (bf16*)(w + 12 * MB);
    bf16* attnb  = (bf16*)(w + 0);
    float* Opart = (float*)(w + 32 * MB);     // 512 * 4096 f32 = 8 MiB
    float* mlbuf = (float*)(w + 48 * MB);     // 512 * 128 f32 = 256 KiB
    int*   cnt   = (int*)(w + 49 * MB);       // 256 pair counters
    bf16* allh   = (bf16*)d_out;              // [2][2048][1024] bf16 = 8 MiB
    bf16* preV   = allh + (size_t)NT * DD;    // in-place over allh_v
    bf16* Qb     = (bf16*)d_out;              // over dead allh_qk
    float* out   = (float*)d_out;

    // 1) convert1: only what proj needs (x, qk_f, v_f, Wg cat)
    ConvJobs J;
    J.src[0] = x;    J.dst[0] = xb;               J.K[0] = 0;    J.R[0] = 0;    J.G[0] = 0;
    J.src[1] = qk_f; J.dst[1] = fbt;              J.K[1] = 1024; J.R[1] = 128;  J.G[1] = 8;
    J.src[2] = v_f;  J.dst[2] = fbt + 1024*1024;  J.K[2] = 1024; J.R[2] = 128;  J.G[2] = 8;
    J.src[3] = Wg_q; J.dst[3] = wg_bt;            J.K[3] = 1024; J.R[3] = 256;  J.G[3] = 1;
    J.src[4] = Wg_k; J.dst[4] = wg_bt + 256*1024; J.K[4] = 1024; J.R[4] = 256;  J.G[4] = 1;
    J.src[5] = Wg_v; J.dst[5] = wg_bt + 2*256*1024; J.K[5] = 1024; J.R[5] = 256; J.G[5] = 1;
    int tiles[6] = {512, 1024, 1024, 256, 256, 256};
    int cum = 0;
    for (int i = 0; i < 6; ++i) { cum += tiles[i]; J.tEnd[i] = cum; }
    for (int i = 6; i < 9; ++i) { J.tEnd[i] = cum; J.src[i] = nullptr; J.dst[i] = nullptr; J.K[i] = J.R[i] = J.G[i] = 0; }
    convert_kernel<<<cum, 256, 0, stream>>>(J);

    // 2) proj: 352 128^2-pipelined GEMM blocks + 3072 conv2 backfill blocks
    ProjArgs Pp;
    Pp.xb = xb; Pp.f0 = fbt; Pp.f1 = fbt + 1024*1024; Pp.wg = wg_bt;
    Pp.allh0 = allh; Pp.allh1 = allh + (size_t)NT * DD; Pp.lg = logits;
    Pp.csrc[0] = qk_r; Pp.csrc[1] = v_r; Pp.csrc[2] = W_O;
    Pp.cdst[0] = qkr_bt; Pp.cdst[1] = vr_bt; Pp.cdst[2] = wo_bt;
    mfma_proj<<<dim3(3424), 256, 0, stream>>>(Pp);

    // 3) fused gates + combine + make_pre (shuffle softmax; preV in-place)
    gate_combine<<<NT, 256, 0, stream>>>(logits, allh, preQ, preK, preV);

    // 4) restore: 384 128^2-pipelined blocks, 3 jobs (+ zero flash counters)
    RestZ Pr;
    Pr.A[0] = preQ; Pr.A[1] = preK; Pr.A[2] = preV;
    Pr.Bt[0] = qkr_bt; Pr.Bt[1] = qkr_bt; Pr.Bt[2] = vr_bt;
    Pr.C[0] = Qb; Pr.C[1] = Kb; Pr.C[2] = Vb;
    mfma_restore<<<dim3(384), 256, 0, stream>>>(Pr, cnt);

    // 5) flash attention, hybrid split-kt + in-kernel merge (768 blocks)
    flash_attn_hybrid<<<dim3(768), 256, 0, stream>>>(Qb, Kb, Vb, attnb,
                                                     Opart, mlbuf, cnt);

    // 6) out = attnb @ W_O (2-deep pipelined 64x64 tiles, 512 blocks)
    mfma_wo<<<dim3(512), 256, 0, stream>>>(attnb, wo_bt, out);
}

// Round 13
// 171.455 us; speedup vs baseline: 1.5111x; 1.5111x over previous
//
#include <hip/hip_runtime.h>
#include <hip/hip_bf16.h>

// Problem constants
#define BB 2
#define SS 1024
#define DD 1024
#define NH 16
#define DH 64
#define MM 8
#define RR 128
#define NN 256
#define NT (BB*SS)          // 2048 tokens

using bf16 = __hip_bfloat16;

typedef __attribute__((ext_vector_type(8))) short short8;   // 8 bf16 (4 VGPRs) MFMA A/B frag
typedef __attribute__((ext_vector_type(4))) short short4v;  // 8-byte unit
typedef __attribute__((ext_vector_type(4))) float f32x4;    // MFMA C/D frag

// raw v_exp_f32 (2^x)
#define EXP2F(x) __builtin_amdgcn_exp2f(x)

// async 16B global->LDS (lane i lands at ldsbase + i*16; ldsbase wave-uniform)
#define GLD16(g, l) __builtin_amdgcn_global_load_lds( \
    (const __attribute__((address_space(1))) void*)(g), \
    (__attribute__((address_space(3))) void*)(l), 16, 0, 0)

// Load 8 bf16 (as shorts) from LDS via two 8B reads (base only 8B-aligned).
__device__ __forceinline__ short8 lds_load8(const short* p) {
    short4v a = *(const short4v*)p;
    short4v b = *(const short4v*)(p + 4);
    short8 r;
    r[0] = a[0]; r[1] = a[1]; r[2] = a[2]; r[3] = a[3];
    r[4] = b[0]; r[5] = b[1]; r[6] = b[2]; r[7] = b[3];
    return r;
}

// ---- staging helper: NR rows x 64 cols bf16, GLD16 + XOR chunk swizzle ----
template <int NR>
__device__ __forceinline__ void stage_tile(const bf16* __restrict__ src, int k0,
                                           bf16* lds, int wave, int lane) {
#pragma unroll
    for (int i = 0; i < NR / 32; ++i) {
        const int L = i * 256 + wave * 64 + lane;
        const int row = L >> 3;
        const int gch = (L & 7) ^ ((row >> 1) & 7);
        GLD16(src + (size_t)row * DD + k0 + gch * 8, &lds[(i * 256 + wave * 64) * 8]);
    }
}

// MFMA fragment from swizzled LDS tile: row rc, k-slot (kk*4+quad)
__device__ __forceinline__ short8 fragld(const bf16* lds, int rc, int kk, int quad) {
    int slot = (kk * 4 + quad) ^ ((rc >> 1) & 7);
    return *(const short8*)&((const short*)lds)[(rc * 8 + slot) * 8];
}

// -------- 128x128 GEMM body, BK=64, 2-buffer 1-deep prefetch (R8) ---------
// 4 waves (2x2), each 64x64 (4x4 frags). LDS 64 KB -> 2 blocks/CU.
// Prefetch k+1 BEFORE compute k; single __syncthreads per step.
// R12 NOTE: in-kernel split-merge via __threadfence/atomic ticket measured
// +85us (flash 20->117us, HBM 1.3% = stalled): device-scope fences must
// write back non-coherent per-XCD L2s. The separate combine kernel's launch
// boundary IS the cheap fence. Do not fuse the combine.
__device__ __forceinline__ void gemm128_pipe1(
    const bf16* __restrict__ A, const bf16* __restrict__ Bt, bf16* __restrict__ C,
    int Nz, int m0, int n0, bf16* As, bf16* Bs,
    int wave, int lane, int quad, int l15) {
    const int wr = wave >> 1, wc = wave & 1;
    f32x4 acc[4][4];
#pragma unroll
    for (int i = 0; i < 4; ++i)
#pragma unroll
        for (int j = 0; j < 4; ++j) acc[i][j] = (f32x4)0.f;

    const bf16* Ab = A + (size_t)m0 * DD;
    const bf16* Bb = Bt + (size_t)n0 * DD;

    stage_tile<128>(Ab, 0, As, wave, lane);
    stage_tile<128>(Bb, 0, Bs, wave, lane);
    __syncthreads();

    for (int it = 0; it < 16; ++it) {
        const int buf = it & 1;
        const bf16* Asc = As + buf * 8192;
        const bf16* Bsc = Bs + buf * 8192;
        if (it < 15) {   // issue next step's loads first (latency hiding)
            stage_tile<128>(Ab, (it + 1) * 64, As + (buf ^ 1) * 8192, wave, lane);
            stage_tile<128>(Bb, (it + 1) * 64, Bs + (buf ^ 1) * 8192, wave, lane);
        }
#pragma unroll
        for (int kk = 0; kk < 2; ++kk) {
            short8 aF[4], bF[4];
#pragma unroll
            for (int bi = 0; bi < 4; ++bi) aF[bi] = fragld(Asc, wr * 64 + bi * 16 + l15, kk, quad);
#pragma unroll
            for (int bj = 0; bj < 4; ++bj) bF[bj] = fragld(Bsc, wc * 64 + bj * 16 + l15, kk, quad);
#pragma unroll
            for (int bi = 0; bi < 4; ++bi)
#pragma unroll
                for (int bj = 0; bj < 4; ++bj)
                    acc[bi][bj] = __builtin_amdgcn_mfma_f32_16x16x32_bf16(aF[bi], bF[bj], acc[bi][bj], 0, 0, 0);
        }
        __syncthreads();   // drains prefetch (overlapped with compute) + reads
    }

#pragma unroll
    for (int bi = 0; bi < 4; ++bi)
#pragma unroll
        for (int bj = 0; bj < 4; ++bj)
#pragma unroll
            for (int r = 0; r < 4; ++r) {
                int row = m0 + wr * 64 + bi * 16 + quad * 4 + r;
                int col = n0 + wc * 64 + bj * 16 + l15;
                C[(size_t)row * Nz + col] = __float2bfloat16(acc[bi][bj][r]);
            }
}

// ---------------- proj launch: 352 GEMM blocks + conv2 backfill ------------
// GEMM works (XCD-swizzled over 352 = 8x44), 128x128 tiles:
//   wk 0..255:  z = wk>>7 -> allh_qk / allh_v (xb @ f[z]), 16x8 tiles
//   wk 256..351: wg GEMM [2048x768] (16x6 tiles)
// blocks 352..3423: conv2 transpose tiles (qk_r, v_r, W_O), pure-BW backfill.
struct ProjArgs {
    const bf16 *xb, *f0, *f1, *wg;
    bf16 *allh0, *allh1, *lg;
    const float* csrc[3];
    bf16* cdst[3];
};

__global__ __launch_bounds__(256, 2) void mfma_proj(ProjArgs P) {
    __shared__ __align__(16) char smem[65536];   // 2x(128x64) x 2 (A,B) bf16
    const int bidx = blockIdx.x;
    const int tid = threadIdx.x;

    if (bidx >= 352) {   // ---- conv2 transpose path (K=R=1024, G=1) ----
        float (*tile)[33] = (float(*)[33])smem;
        const int cb = bidx - 352;
        const int j = cb >> 10;
        const int t = cb & 1023;
        const int kb = t >> 5, rb = t & 31;
        const int tx = tid & 31, ty0 = tid >> 5;
        const float* s = P.csrc[j] + ((size_t)(kb * 32) * 1024) + rb * 32 + tx;
#pragma unroll
        for (int p = 0; p < 4; ++p)
            tile[ty0 + p * 8][tx] = s[(size_t)(ty0 + p * 8) * 1024];
        __syncthreads();
        bf16* dd = P.cdst[j] + ((size_t)(rb * 32) * 1024) + kb * 32 + tx;
#pragma unroll
        for (int p = 0; p < 4; ++p)
            dd[(size_t)(ty0 + p * 8) * 1024] = __float2bfloat16(tile[tx][ty0 + p * 8]);
        return;
    }

    bf16* As = (bf16*)smem;          // 2 x 128*64
    bf16* Bs = As + 2 * 128 * 64;    // 2 x 128*64
    const int wave = tid >> 6, lane = tid & 63;
    const int quad = lane >> 4, l15 = lane & 15;
    const int wk = (bidx & 7) * 44 + (bidx >> 3);   // XCD swizzle (352 = 8x44)
    if (wk < 256) {
        const int z = wk >> 7;
        const int r = wk & 127;
        gemm128_pipe1(P.xb, z ? P.f1 : P.f0, z ? P.allh1 : P.allh0, 1024,
                      (r >> 3) * 128, (r & 7) * 128, As, Bs, wave, lane, quad, l15);
    } else {
        const int r = wk - 256;
        gemm128_pipe1(P.xb, P.wg, P.lg, 768, (r / 6) * 128, (r % 6) * 128,
                      As, Bs, wave, lane, quad, l15);
    }
}

// ---------------- restore launch: 384 blocks, 3 jobs, 128x128 --------------
struct RestZ {
    const bf16* A[3];
    const bf16* Bt[3];
    bf16* C[3];
};

__global__ __launch_bounds__(256, 2) void mfma_restore(RestZ R) {
    __shared__ __align__(16) char smem[65536];
    bf16* As = (bf16*)smem;
    bf16* Bs = As + 2 * 128 * 64;
    const int tid = threadIdx.x;
    const int wave = tid >> 6, lane = tid & 63;
    const int quad = lane >> 4, l15 = lane & 15;
    const int wk = (blockIdx.x & 7) * 48 + (blockIdx.x >> 3);   // 384 = 8x48
    const int z = wk >> 7;
    const int r = wk & 127;
    gemm128_pipe1(R.A[z], R.Bt[z], R.C[z], DD, (r >> 3) * 128, (r & 7) * 128,
                  As, Bs, wave, lane, quad, l15);
}

// ---------- W_O: 2-deep pipelined 64x64 tiles, 512 blocks, f32 out ---------
__global__ __launch_bounds__(256, 3) void mfma_wo(
    const bf16* __restrict__ A, const bf16* __restrict__ Bt, float* __restrict__ C) {
    __shared__ __align__(16) bf16 As[3 * 64 * 64];
    __shared__ __align__(16) bf16 Bs[3 * 64 * 64];
    const int tid = threadIdx.x;
    const int wave = tid >> 6, lane = tid & 63;
    const int quad = lane >> 4, l15 = lane & 15;
    const int wr = wave >> 1, wc = wave & 1;
    const int wk = (blockIdx.x & 7) * 64 + (blockIdx.x >> 3);   // 512 = 8x64
    const int m0 = (wk >> 4) * 64, n0 = (wk & 15) * 64;

    f32x4 acc[2][2];
#pragma unroll
    for (int i = 0; i < 2; ++i)
#pragma unroll
        for (int j = 0; j < 2; ++j) acc[i][j] = (f32x4)0.f;

    const bf16* Ab = A + (size_t)m0 * DD;
    const bf16* Bb = Bt + (size_t)n0 * DD;

    stage_tile<64>(Ab, 0, As, wave, lane);
    stage_tile<64>(Bb, 0, Bs, wave, lane);
    stage_tile<64>(Ab, 64, As + 4096, wave, lane);
    stage_tile<64>(Bb, 64, Bs + 4096, wave, lane);

    int cur = 0;
    for (int it = 0; it < 16; ++it) {
        const int k0 = it * 64;
        int nxt = cur + 2; if (nxt >= 3) nxt -= 3;
        if (it < 14) {
            stage_tile<64>(Ab, k0 + 128, As + nxt * 4096, wave, lane);
            stage_tile<64>(Bb, k0 + 128, Bs + nxt * 4096, wave, lane);
            asm volatile("s_waitcnt vmcnt(8)" ::: "memory");
        } else if (it == 14) {
            asm volatile("s_waitcnt vmcnt(4)" ::: "memory");
        } else {
            asm volatile("s_waitcnt vmcnt(0)" ::: "memory");
        }
        __builtin_amdgcn_s_barrier();

        const bf16* Asc = As + cur * 4096;
        const bf16* Bsc = Bs + cur * 4096;
#pragma unroll
        for (int kk = 0; kk < 2; ++kk) {
            short8 aF[2], bF[2];
#pragma unroll
            for (int bi = 0; bi < 2; ++bi) aF[bi] = fragld(Asc, wr * 32 + bi * 16 + l15, kk, quad);
#pragma unroll
            for (int bj = 0; bj < 2; ++bj) bF[bj] = fragld(Bsc, wc * 32 + bj * 16 + l15, kk, quad);
#pragma unroll
            for (int bi = 0; bi < 2; ++bi)
#pragma unroll
                for (int bj = 0; bj < 2; ++bj)
                    acc[bi][bj] = __builtin_amdgcn_mfma_f32_16x16x32_bf16(aF[bi], bF[bj], acc[bi][bj], 0, 0, 0);
        }
        __builtin_amdgcn_s_barrier();
        cur = cur + 1; if (cur == 3) cur = 0;
    }
#pragma unroll
    for (int bi = 0; bi < 2; ++bi)
#pragma unroll
        for (int bj = 0; bj < 2; ++bj)
#pragma unroll
            for (int r = 0; r < 4; ++r) {
                int row = m0 + wr * 32 + bi * 16 + quad * 4 + r;
                int col = n0 + wc * 32 + bj * 16 + l15;
                C[(size_t)row * DD + col] = acc[bi][bj][r];
            }
}

// ---------------- convert1: inputs proj needs (x, qk_f, v_f, Wg) -----------
struct ConvJobs {
    const float* src[9];
    bf16* dst[9];
    int K[9], R[9], G[9];
    int tEnd[9];
};

__global__ void convert_kernel(ConvJobs J) {
    __shared__ float tile[32][33];
    const int b = blockIdx.x;
    int j = 0;
    while (j < 8 && b >= J.tEnd[j]) ++j;
    const int local = b - (j > 0 ? J.tEnd[j - 1] : 0);
    const float* src = J.src[j];
    bf16* dst = J.dst[j];
    const int tid = threadIdx.x;

    if (J.G[j] == 0) {
        size_t base = (size_t)local * 4096 + (size_t)tid * 16;
        const float4* s4 = (const float4*)(src + base);
        short* d = (short*)(dst + base);
#pragma unroll
        for (int c = 0; c < 4; ++c) {
            float4 v = s4[c];
            short4v o;
            bf16 t0 = __float2bfloat16(v.x); o[0] = *(short*)&t0;
            bf16 t1 = __float2bfloat16(v.y); o[1] = *(short*)&t1;
            bf16 t2 = __float2bfloat16(v.z); o[2] = *(short*)&t2;
            bf16 t3 = __float2bfloat16(v.w); o[3] = *(short*)&t3;
            *(short4v*)(d + c * 4) = o;
        }
    } else {
        const int Kj = J.K[j], Rj = J.R[j];
        const int Rb = Rj >> 5, Kb = Kj >> 5;
        const int perG = Kb * Rb;
        const int g = local / perG;
        const int rem = local - g * perG;
        const int kb = rem / Rb, rb = rem - kb * Rb;
        const int tx = tid & 31, ty0 = tid >> 5;
        const float* s = src + ((size_t)(g * Kj + kb * 32) * Rj) + rb * 32 + tx;
#pragma unroll
        for (int p = 0; p < 4; ++p)
            tile[ty0 + p * 8][tx] = s[(size_t)(ty0 + p * 8) * Rj];
        __syncthreads();
        bf16* dd = dst + ((size_t)(g * Rj + rb * 32) * Kj) + kb * 32 + tx;
#pragma unroll
        for (int p = 0; p < 4; ++p)
            dd[(size_t)(ty0 + p * 8) * Kj] = __float2bfloat16(tile[tx][ty0 + p * 8]);
    }
}

// ---------------- fused gates + combine + make_pre (shuffle softmax) -------
__global__ void gate_combine(const bf16* __restrict__ logitsAll,
                             const bf16* __restrict__ allh,
                             bf16* __restrict__ preQ, bf16* __restrict__ preK,
                             bf16* __restrict__ preV) {
    const int t = blockIdx.x;
    const int n = threadIdx.x;   // 256
    const int wave = n >> 6, lane = n & 63;
    __shared__ float wred[3][4];
    __shared__ float sred[3][4];
    __shared__ float gred[3][8];

    float v[3], e[3];
#pragma unroll
    for (int z = 0; z < 3; ++z)
        v[z] = __bfloat162float(logitsAll[(size_t)t * 768 + z * 256 + n]);

    float mz[3];
#pragma unroll
    for (int z = 0; z < 3; ++z) {
        mz[z] = v[z];
#pragma unroll
        for (int off = 1; off <= 32; off <<= 1)
            mz[z] = fmaxf(mz[z], __shfl_xor(mz[z], off));
    }
    if (lane == 0) {
#pragma unroll
        for (int z = 0; z < 3; ++z) wred[z][wave] = mz[z];
    }
    __syncthreads();
    float gmax[3];
#pragma unroll
    for (int z = 0; z < 3; ++z)
        gmax[z] = fmaxf(fmaxf(wred[z][0], wred[z][1]), fmaxf(wred[z][2], wred[z][3]));

    float ws[3];
#pragma unroll
    for (int z = 0; z < 3; ++z) {
        e[z] = __expf(v[z] - gmax[z]);
        ws[z] = e[z];
#pragma unroll
        for (int off = 1; off <= 32; off <<= 1)
            ws[z] += __shfl_xor(ws[z], off);
    }
    if (lane == 0) {
#pragma unroll
        for (int z = 0; z < 3; ++z) sred[z][wave] = ws[z];
    }
    float gs[3];
#pragma unroll
    for (int z = 0; z < 3; ++z) {
        gs[z] = e[z];
#pragma unroll
        for (int off = 1; off <= 16; off <<= 1)
            gs[z] += __shfl_xor(gs[z], off);
    }
    __syncthreads();
    float total[3];
#pragma unroll
    for (int z = 0; z < 3; ++z)
        total[z] = sred[z][0] + sred[z][1] + sred[z][2] + sred[z][3];
    if ((n & 31) == 0) {
#pragma unroll
        for (int z = 0; z < 3; ++z) gred[z][n >> 5] = gs[z] / total[z];
    }
    __syncthreads();

    float gv[3][8];
#pragma unroll
    for (int z = 0; z < 3; ++z) {
        float tot = 0.f;
#pragma unroll
        for (int m = 0; m < 8; ++m) tot += gred[z][m];
        float inv = 1.0f / (tot + 1e-8f);
#pragma unroll
        for (int m = 0; m < 8; ++m) gv[z][m] = gred[z][m] * inv;
    }

    const int r0 = n & 127;
    const int half = n >> 7;
    const bf16* src_qk = allh + (size_t)t * 1024;
    const bf16* src_v  = allh + (size_t)NT * DD + (size_t)t * 1024;
    float hq = 0.f, hk = 0.f, hv = 0.f;
#pragma unroll
    for (int m = 0; m < 8; ++m) {
        float aqk = __bfloat162float(src_qk[m * 128 + r0]);
        float av  = __bfloat162float(src_v[m * 128 + r0]);
        hq += aqk * gv[0][m];
        hk += aqk * gv[1][m];
        hv += av  * gv[2][m];
    }
    __syncthreads();   // all allh_v reads complete before in-place preV writes
#pragma unroll
    for (int mm = 0; mm < 4; ++mm) {
        int m = half * 4 + mm;
        size_t o = (size_t)t * 1024 + m * 128 + r0;
        preQ[o] = __float2bfloat16(hq * gv[0][m]);
        preK[o] = __float2bfloat16(hk * gv[1][m]);
        preV[o] = __float2bfloat16(hv * gv[2][m]);
    }
}

// -------------- Flash attention, hybrid split-kt --------------------------
// qt>=8 split into two <=8-iter halves (f32 partials); qt<8 unsplit (direct
// bf16 out). 768 blocks dispatched longest-first => makespan ~9 iters.
#define LDK 68

// rank -> work: (split<<5) | (qt<<1) | half, ordered by descending kt-iters
__device__ const int FW24[24] = {
    62, 63, 60, 61, 14,    // len 8: S15h0 S15h1 S14h0 S14h1 U7
    58, 59, 56, 12,        // len 7: S13h0 S13h1 S12h0 U6
    57, 54, 55, 52, 10,    // len 6: S12h1 S11h0 S11h1 S10h0 U5
    53, 50, 51, 48, 8,     // len 5: S10h1 S9h0 S9h1 S8h0 U4
    49, 6,                 // len 4: S8h1 U3
    4, 2, 0                // U2 U1 U0
};

__global__ __launch_bounds__(256) void flash_attn_hybrid(
    const bf16* __restrict__ Q, const bf16* __restrict__ K,
    const bf16* __restrict__ V, bf16* __restrict__ out,
    float* __restrict__ Opart, float* __restrict__ ml) {
    const int bx = blockIdx.x;
    const int e = FW24[bx >> 5];
    const int bh = bx & 31;
    const int split = e >> 5;
    const int qt = (e >> 1) & 15;
    const int half = e & 1;
    const int h0 = (qt + 2) >> 1;
    const int kt_lo = (split && half) ? h0 : 0;
    const int kt_hi = (split && !half) ? h0 : (qt + 1);
    const int b = bh >> 4;
    const int h = bh & 15;

    const int tid = threadIdx.x;
    const int wave = tid >> 6;
    const int lane = tid & 63;
    const int quad = lane >> 4;
    const int l15 = lane & 15;

    __shared__ short Ks[2][64 * 64];      // 16 KB, GLD16 + XOR swizzle
    __shared__ short Vt[2][64 * LDK];     // 17 KB, transposed
    __shared__ short Ps[4 * 16 * LDK];    // per-wave P[m][kr]

    const int q_row = qt * 64 + wave * 16 + l15;
    const bf16* qptr = Q + (size_t)(b * SS + q_row) * DD + h * DH + quad * 8;
    short8 aq0 = *(const short8*)qptr;
    short8 aq1 = *(const short8*)(qptr + 32);

    // V staging geometry (per thread)
    const int krp = tid & 31;
    const int dhb = (tid >> 5) * 8;

    float m_r[4], l_r[4];
    f32x4 o[4];
#pragma unroll
    for (int r = 0; r < 4; ++r) { m_r[r] = -3.0e38f; l_r[r] = 0.f; }
#pragma unroll
    for (int cc = 0; cc < 4; ++cc) o[cc] = (f32x4)0.f;

    const float SCL2 = 0.18033688f;   // 0.125 * log2(e)

    // ---- prologue: stage tile kt_lo into buf 0 ----
    {
#pragma unroll
        for (int i = 0; i < 2; ++i) {
            const int L = i * 256 + wave * 64 + lane;
            const int row = L >> 3;
            const int gch = (L & 7) ^ ((row >> 1) & 7);
            GLD16(K + (size_t)(b * SS + kt_lo * 64 + row) * DD + h * DH + gch * 8,
                  &Ks[0][(i * 256 + wave * 64) * 8]);
        }
        const bf16* s0 = V + (size_t)(b * SS + kt_lo * 64 + 2 * krp) * DD + h * DH + dhb;
        short8 r0 = *(const short8*)s0;
        short8 r1 = *(const short8*)(s0 + DD);
#pragma unroll
        for (int i = 0; i < 8; ++i) {
            unsigned int pk = (unsigned short)r0[i] | ((unsigned int)(unsigned short)r1[i] << 16);
            *(unsigned int*)&Vt[0][(dhb + i) * LDK + 2 * krp] = pk;
        }
        __syncthreads();
    }

    for (int kt = kt_lo; kt < kt_hi; ++kt) {
        const int buf = (kt - kt_lo) & 1;
        const bool pf = (kt + 1 < kt_hi);
        short8 pr0, pr1;
        if (pf) {
            // issue next K tile (async direct-to-LDS) and next V loads (VGPR)
#pragma unroll
            for (int i = 0; i < 2; ++i) {
                const int L = i * 256 + wave * 64 + lane;
                const int row = L >> 3;
                const int gch = (L & 7) ^ ((row >> 1) & 7);
                GLD16(K + (size_t)(b * SS + (kt + 1) * 64 + row) * DD + h * DH + gch * 8,
                      &Ks[buf ^ 1][(i * 256 + wave * 64) * 8]);
            }
            const bf16* s0 = V + (size_t)(b * SS + (kt + 1) * 64 + 2 * krp) * DD + h * DH + dhb;
            pr0 = *(const short8*)s0;
            pr1 = *(const short8*)(s0 + DD);
        }

        // ---- compute current tile ----
        const short* KsB = Ks[buf];
        f32x4 s[4];
#pragma unroll
        for (int cc = 0; cc < 4; ++cc) {
            int n = cc * 16 + l15;
            int sl0 = quad ^ ((n >> 1) & 7);
            int sl1 = (quad + 4) ^ ((n >> 1) & 7);
            short8 bk0 = *(const short8*)&KsB[(n * 8 + sl0) * 8];
            short8 bk1 = *(const short8*)&KsB[(n * 8 + sl1) * 8];
            f32x4 acc = (f32x4)0.f;
            acc = __builtin_amdgcn_mfma_f32_16x16x32_bf16(aq0, bk0, acc, 0, 0, 0);
            acc = __builtin_amdgcn_mfma_f32_16x16x32_bf16(aq1, bk1, acc, 0, 0, 0);
            s[cc] = acc;
        }

        const bool diag = (kt == qt);
#pragma unroll
        for (int cc = 0; cc < 4; ++cc) {
#pragma unroll
            for (int r = 0; r < 4; ++r) {
                float v = s[cc][r] * SCL2;
                if (diag) {
                    int row_rel = wave * 16 + quad * 4 + r;
                    int col_rel = cc * 16 + l15;
                    if (col_rel > row_rel) v = -3.0e38f;
                }
                s[cc][r] = v;
            }
        }

        // tile row-max
        float mx[4];
#pragma unroll
        for (int r = 0; r < 4; ++r) {
            float m2 = fmaxf(fmaxf(s[0][r], s[1][r]), fmaxf(s[2][r], s[3][r]));
            m2 = fmaxf(m2, __shfl_xor(m2, 1));
            m2 = fmaxf(m2, __shfl_xor(m2, 2));
            m2 = fmaxf(m2, __shfl_xor(m2, 4));
            m2 = fmaxf(m2, __shfl_xor(m2, 8));
            mx[r] = m2;
        }
        // defer-max: only pay alpha-exp + o/l rescale when max grew by >8
        bool grew = false;
#pragma unroll
        for (int r = 0; r < 4; ++r) grew = grew || (mx[r] > m_r[r] + 8.f);
        float alpha[4];
        const bool need = __any(grew);
        if (need) {
#pragma unroll
            for (int r = 0; r < 4; ++r) {
                float nm = fmaxf(m_r[r], mx[r]);
                alpha[r] = EXP2F(m_r[r] - nm);
                m_r[r] = nm;
            }
        }

        float p[4][4];
#pragma unroll
        for (int r = 0; r < 4; ++r) {
            float rs = 0.f;
#pragma unroll
            for (int cc = 0; cc < 4; ++cc) {
                float e2 = EXP2F(s[cc][r] - m_r[r]);
                p[cc][r] = e2;
                rs += e2;
            }
            rs += __shfl_xor(rs, 1);
            rs += __shfl_xor(rs, 2);
            rs += __shfl_xor(rs, 4);
            rs += __shfl_xor(rs, 8);
            if (need) l_r[r] = l_r[r] * alpha[r] + rs;
            else      l_r[r] += rs;
        }
        if (need) {
#pragma unroll
            for (int cc = 0; cc < 4; ++cc)
#pragma unroll
                for (int r = 0; r < 4; ++r) o[cc][r] *= alpha[r];
        }

        // P: C-layout -> wave-private LDS slab -> A-layout (no barrier needed)
        short* pw = &Ps[wave * 16 * LDK];
#pragma unroll
        for (int cc = 0; cc < 4; ++cc)
#pragma unroll
            for (int r = 0; r < 4; ++r) {
                bf16 hb = __float2bfloat16(p[cc][r]);
                pw[(quad * 4 + r) * LDK + cc * 16 + l15] = *(short*)&hb;
            }

        short8 ap0 = lds_load8(&pw[l15 * LDK + quad * 8]);
        short8 ap1 = lds_load8(&pw[l15 * LDK + 32 + quad * 8]);

        const short* VtB = Vt[buf];
#pragma unroll
        for (int cc = 0; cc < 4; ++cc) {
            short8 bv0 = lds_load8(&VtB[(cc * 16 + l15) * LDK + quad * 8]);
            short8 bv1 = lds_load8(&VtB[(cc * 16 + l15) * LDK + 32 + quad * 8]);
            o[cc] = __builtin_amdgcn_mfma_f32_16x16x32_bf16(ap0, bv0, o[cc], 0, 0, 0);
            o[cc] = __builtin_amdgcn_mfma_f32_16x16x32_bf16(ap1, bv1, o[cc], 0, 0, 0);
        }

        // ---- write V prefetch into the other buffer, then the ONE barrier ----
        if (pf) {
#pragma unroll
            for (int i = 0; i < 8; ++i) {
                unsigned int pk = (unsigned short)pr0[i] | ((unsigned int)(unsigned short)pr1[i] << 16);
                *(unsigned int*)&Vt[buf ^ 1][(dhb + i) * LDK + 2 * krp] = pk;
            }
        }
        __syncthreads();
    }

    if (!split) {
        // ---- normalize in-register and write bf16 directly ----
        float inv[4];
#pragma unroll
        for (int r = 0; r < 4; ++r) inv[r] = 1.0f / l_r[r];
#pragma unroll
        for (int cc = 0; cc < 4; ++cc)
#pragma unroll
            for (int r = 0; r < 4; ++r) {
                int row = qt * 64 + wave * 16 + quad * 4 + r;
                out[(size_t)(b * SS + row) * DD + h * DH + cc * 16 + l15] =
                    __float2bfloat16(o[cc][r] * inv[r]);
            }
    } else {
        // ---- write partials (unnormalized O, m, l in log2 domain) ----
        const int idx = (bh * 8 + (qt - 8)) * 2 + half;
        float* ob = Opart + (size_t)idx * 4096;
#pragma unroll
        for (int cc = 0; cc < 4; ++cc)
#pragma unroll
            for (int r = 0; r < 4; ++r) {
                int row = wave * 16 + quad * 4 + r;
                ob[row * 64 + cc * 16 + l15] = o[cc][r];
            }
        if (l15 == 0) {
#pragma unroll
            for (int r = 0; r < 4; ++r) {
                int row = wave * 16 + quad * 4 + r;
                ml[(size_t)idx * 128 + row] = m_r[r];
                ml[(size_t)idx * 128 + 64 + row] = l_r[r];
            }
        }
    }
}

// Merge the two kt-halves for qt>=8: out = (O0*w0+O1*w1)/(l0*w0+l1*w1),
// w_i = exp2(m_i - max) (log2 domain). 256 blocks = 32 bh x 8 qt.
__global__ void attn_combine(const float* __restrict__ Opart,
                             const float* __restrict__ ml,
                             bf16* __restrict__ out) {
    const int bidx = blockIdx.x;
    const int bh = bidx & 31;
    const int qt = (bidx >> 5) + 8;
    const int b = bh >> 4;
    const int h = bh & 15;
    const int tid = threadIdx.x;       // 256
    const int row = tid >> 2;
    const int cg = tid & 3;

    const int p0 = (bh * 8 + (qt - 8)) * 2;
    const int p1 = p0 + 1;
    float m0 = ml[(size_t)p0 * 128 + row], l0 = ml[(size_t)p0 * 128 + 64 + row];
    float m1 = ml[(size_t)p1 * 128 + row], l1 = ml[(size_t)p1 * 128 + 64 + row];
    float ms = fmaxf(m0, m1);
    float w0 = EXP2F(m0 - ms), w1 = EXP2F(m1 - ms);
    float inv = 1.0f / (l0 * w0 + l1 * w1);

    const float* o0 = Opart + (size_t)p0 * 4096 + row * 64 + cg * 16;
    const float* o1 = Opart + (size_t)p1 * 4096 + row * 64 + cg * 16;
    short out16[16];
#pragma unroll
    for (int j = 0; j < 16; j += 4) {
        float4 a = *(const float4*)(o0 + j);
        float4 bb = *(const float4*)(o1 + j);
        bf16 t0 = __float2bfloat16((a.x * w0 + bb.x * w1) * inv); out16[j] = *(short*)&t0;
        bf16 t1 = __float2bfloat16((a.y * w0 + bb.y * w1) * inv); out16[j + 1] = *(short*)&t1;
        bf16 t2 = __float2bfloat16((a.z * w0 + bb.z * w1) * inv); out16[j + 2] = *(short*)&t2;
        bf16 t3 = __float2bfloat16((a.w * w0 + bb.w * w1) * inv); out16[j + 3] = *(short*)&t3;
    }
    short* dst = (short*)(out + (size_t)(b * SS + qt * 64 + row) * DD + h * DH + cg * 16);
    *(short8*)dst = *(short8*)&out16[0];
    *(short8*)(dst + 8) = *(short8*)&out16[8];
}

extern "C" void kernel_launch(void* const* d_in, const int* in_sizes, int n_in,
                              void* d_out, int out_size, void* d_ws, size_t ws_size,
                              hipStream_t stream) {
    const float* x    = (const float*)d_in[0];
    const float* qk_f = (const float*)d_in[1];
    const float* qk_r = (const float*)d_in[2];
    const float* v_f  = (const float*)d_in[3];
    const float* v_r  = (const float*)d_in[4];
    const float* Wg_q = (const float*)d_in[5];
    const float* Wg_k = (const float*)d_in[6];
    const float* Wg_v = (const float*)d_in[7];
    const float* W_O  = (const float*)d_in[8];

    // Workspace (256 MiB). Layout:
    //  0..4    xb      -> preQ      -> attnb
    //  4..8    wg_bt(4..5.5)+pad    -> preK
    //  5.5..9.5 fbt    (dead after proj)
    //  8..12           -> Kb
    //  9.5..12.5 logits (dead after gate_combine)
    //  12..16          -> Vb
    //  16..18 qkr_bt | 18..20 vr_bt | 20..22 wo_bt (stable)
    //  32..40 Opart (512 x 16KB f32) | 48..48.25 ml
    // d_out: allh [0..8 MiB] -> preV in-place over allh_v -> Qb [0..4] -> f32 out
    char* w = (char*)d_ws;
    const size_t MB = 1 << 20;
    bf16* xb     = (bf16*)(w + 0);
    bf16* wg_bt  = (bf16*)(w + 4 * MB);
    bf16* fbt    = (bf16*)(w + (size_t)(5.5 * MB));
    bf16* logits = (bf16*)(w + (size_t)(9.5 * MB));   // [2048][768] = 3 MiB
    bf16* qkr_bt = (bf16*)(w + 16 * MB);
    bf16* vr_bt  = (bf16*)(w + 18 * MB);
    bf16* wo_bt  = (bf16*)(w + 20 * MB);
    bf16* preQ   = (bf16*)(w + 0);
    bf16* preK   = (bf16*)(w + 4 * MB);
    bf16* Kb     = (bf16*)(w + 8 * MB);
    bf16* Vb     = (bf16*)(w + 12 * MB);
    bf16* attnb  = (bf16*)(w + 0);
    float* Opart = (float*)(w + 32 * MB);     // 512 * 4096 f32 = 8 MiB
    float* mlbuf = (float*)(w + 48 * MB);     // 512 * 128 f32 = 256 KiB
    bf16* allh   = (bf16*)d_out;              // [2][2048][1024] bf16 = 8 MiB
    bf16* preV   = allh + (size_t)NT * DD;    // in-place over allh_v
    bf16* Qb     = (bf16*)d_out;              // over dead allh_qk
    float* out   = (float*)d_out;

    // 1) convert1: only what proj needs (x, qk_f, v_f, Wg cat)
    ConvJobs J;
    J.src[0] = x;    J.dst[0] = xb;               J.K[0] = 0;    J.R[0] = 0;    J.G[0] = 0;
    J.src[1] = qk_f; J.dst[1] = fbt;              J.K[1] = 1024; J.R[1] = 128;  J.G[1] = 8;
    J.src[2] = v_f;  J.dst[2] = fbt + 1024*1024;  J.K[2] = 1024; J.R[2] = 128;  J.G[2] = 8;
    J.src[3] = Wg_q; J.dst[3] = wg_bt;            J.K[3] = 1024; J.R[3] = 256;  J.G[3] = 1;
    J.src[4] = Wg_k; J.dst[4] = wg_bt + 256*1024; J.K[4] = 1024; J.R[4] = 256;  J.G[4] = 1;
    J.src[5] = Wg_v; J.dst[5] = wg_bt + 2*256*1024; J.K[5] = 1024; J.R[5] = 256; J.G[5] = 1;
    int tiles[6] = {512, 1024, 1024, 256, 256, 256};
    int cum = 0;
    for (int i = 0; i < 6; ++i) { cum += tiles[i]; J.tEnd[i] = cum; }
    for (int i = 6; i < 9; ++i) { J.tEnd[i] = cum; J.src[i] = nullptr; J.dst[i] = nullptr; J.K[i] = J.R[i] = J.G[i] = 0; }
    convert_kernel<<<cum, 256, 0, stream>>>(J);

    // 2) proj: 352 128^2-pipelined GEMM blocks + 3072 conv2 backfill blocks
    ProjArgs Pp;
    Pp.xb = xb; Pp.f0 = fbt; Pp.f1 = fbt + 1024*1024; Pp.wg = wg_bt;
    Pp.allh0 = allh; Pp.allh1 = allh + (size_t)NT * DD; Pp.lg = logits;
    Pp.csrc[0] = qk_r; Pp.csrc[1] = v_r; Pp.csrc[2] = W_O;
    Pp.cdst[0] = qkr_bt; Pp.cdst[1] = vr_bt; Pp.cdst[2] = wo_bt;
    mfma_proj<<<dim3(3424), 256, 0, stream>>>(Pp);

    // 3) fused gates + combine + make_pre (shuffle softmax; preV in-place)
    gate_combine<<<NT, 256, 0, stream>>>(logits, allh, preQ, preK, preV);

    // 4) restore: 384 128^2-pipelined blocks, 3 jobs
    RestZ Pr;
    Pr.A[0] = preQ; Pr.A[1] = preK; Pr.A[2] = preV;
    Pr.Bt[0] = qkr_bt; Pr.Bt[1] = qkr_bt; Pr.Bt[2] = vr_bt;
    Pr.C[0] = Qb; Pr.C[1] = Kb; Pr.C[2] = Vb;
    mfma_restore<<<dim3(384), 256, 0, stream>>>(Pr);

    // 5) flash attention, hybrid split-kt (768 blocks, longest-first)
    flash_attn_hybrid<<<dim3(768), 256, 0, stream>>>(Qb, Kb, Vb, attnb, Opart, mlbuf);

    // 6) merge split halves (qt>=8) -> attnb
    attn_combine<<<dim3(256), 256, 0, stream>>>(Opart, mlbuf, attnb);

    // 7) out = attnb @ W_O (2-deep pipelined 64x64 tiles, 512 blocks)
    mfma_wo<<<dim3(512), 256, 0, stream>>>(attnb, wo_bt, out);
}